// Round 1
// baseline (2111.070 us; speedup 1.0000x reference)
//
#include <hip/hip_runtime.h>
#include <hip/hip_bf16.h>
#include <math.h>

// Problem constants
#define Bb 32
#define Dd 512
#define Ss 512      // NC + Hs*Ws
#define NHh 8
#define DHh 64
#define MLPm 2048
#define NCc 256
#define INNERi 512
#define Mrows (Bb*Ss)   // 16384

typedef __bf16 bf16x8 __attribute__((ext_vector_type(8)));
typedef float floatx4 __attribute__((ext_vector_type(4)));

__device__ __forceinline__ void load_lds16(const void* g, void* l) {
  __builtin_amdgcn_global_load_lds(
      (__attribute__((address_space(1))) void*)(g),
      (__attribute__((address_space(3))) void*)(l), 16, 0, 0);
}

// XOR-swizzled LDS addressing for 64-elem bf16 rows: logical (row, seg8)
// stored at row*64 + ((seg ^ (row&7))<<3). b128 frag reads spread banks.
__device__ __forceinline__ int swz(int row, int seg) {
  return row * 64 + (((seg) ^ (row & 7)) << 3);
}

// ---------------------------------------------------------------------------
// Tiled transpose + fp32->bf16 downcast: in (K,N) fp32 -> out (N,K) bf16
// ---------------------------------------------------------------------------
__global__ void transpose_w(const float* __restrict__ in, __hip_bfloat16* __restrict__ out,
                            int K, int N, size_t in_ls, size_t out_ls)
{
  __shared__ float tile[32][33];
  in  += (size_t)blockIdx.z * in_ls;
  out += (size_t)blockIdx.z * out_ls;
  int n0 = blockIdx.x * 32, k0 = blockIdx.y * 32;
  int tx = threadIdx.x;
  #pragma unroll
  for (int i = threadIdx.y; i < 32; i += 8)
    tile[i][tx] = in[(size_t)(k0 + i) * N + n0 + tx];
  __syncthreads();
  #pragma unroll
  for (int i = threadIdx.y; i < 32; i += 8)
    out[(size_t)(n0 + i) * K + k0 + tx] = __float2bfloat16(tile[tx][i]);
}

// ---------------------------------------------------------------------------
// Prologue: build x[b,s,:] (slots+slot_pos | z^T+pos), then LayerNorm(norm_w/b)
// ---------------------------------------------------------------------------
__global__ void prologue_kernel(const float* __restrict__ z, const float* __restrict__ slots,
                                const float* __restrict__ pos, const float* __restrict__ spos,
                                const float* __restrict__ nw, const float* __restrict__ nb,
                                float* __restrict__ x)
{
  int row = blockIdx.x;            // b*S + s
  int b = row >> 9, s = row & 511;
  int lane = threadIdx.x;
  float v[8];
  float sum = 0.f;
  #pragma unroll
  for (int j = 0; j < 8; ++j) {
    int d = lane + j * 64;
    float t;
    if (s < NCc) t = slots[((size_t)b * NCc + s) * Dd + d] + spos[(size_t)s * Dd + d];
    else {
      int sp = s - NCc;
      t = z[((size_t)b * Dd + d) * 256 + sp] + pos[(size_t)sp * Dd + d];
    }
    v[j] = t; sum += t;
  }
  #pragma unroll
  for (int o = 32; o; o >>= 1) sum += __shfl_xor(sum, o);
  float mean = sum * (1.f / Dd);
  float vs = 0.f;
  #pragma unroll
  for (int j = 0; j < 8; ++j) { float d = v[j] - mean; vs += d * d; }
  #pragma unroll
  for (int o = 32; o; o >>= 1) vs += __shfl_xor(vs, o);
  float rs = rsqrtf(vs * (1.f / Dd) + 1e-5f);
  #pragma unroll
  for (int j = 0; j < 8; ++j) {
    int d = lane + j * 64;
    x[(size_t)row * Dd + d] = (v[j] - mean) * rs * nw[d] + nb[d];
  }
}

// ---------------------------------------------------------------------------
// LayerNorm: x fp32 (rows,512) -> y bf16
// ---------------------------------------------------------------------------
__global__ void ln_kernel(const float* __restrict__ x, const float* __restrict__ w,
                          const float* __restrict__ b, __hip_bfloat16* __restrict__ y)
{
  int row = blockIdx.x * 4 + (threadIdx.x >> 6);
  int lane = threadIdx.x & 63;
  const float* xr = x + (size_t)row * Dd;
  float v[8];
  float sum = 0.f;
  #pragma unroll
  for (int j = 0; j < 8; ++j) { v[j] = xr[lane + j * 64]; sum += v[j]; }
  #pragma unroll
  for (int o = 32; o; o >>= 1) sum += __shfl_xor(sum, o);
  float mean = sum * (1.f / Dd);
  float vs = 0.f;
  #pragma unroll
  for (int j = 0; j < 8; ++j) { float d = v[j] - mean; vs += d * d; }
  #pragma unroll
  for (int o = 32; o; o >>= 1) vs += __shfl_xor(vs, o);
  float rs = rsqrtf(vs * (1.f / Dd) + 1e-5f);
  #pragma unroll
  for (int j = 0; j < 8; ++j) {
    int d = lane + j * 64;
    y[(size_t)row * Dd + d] = __float2bfloat16((v[j] - mean) * rs * w[d] + b[d]);
  }
}

// ---------------------------------------------------------------------------
// bf16 MFMA GEMM (128x128 tile, m97 structure): C(M,N) = A(M,K) @ Bt(N,K)^T
// Kept for the N=512 GEMMs (out-proj, mlp2) where a 256^2 grid would be
// only 128 blocks (half the GPU idle).
// MODE 1: -> f32 out = acc+bias+res
// ---------------------------------------------------------------------------
template <int MODE>
__global__ __launch_bounds__(256, 2)
void gemm_bt(const __hip_bfloat16* __restrict__ A, const __hip_bfloat16* __restrict__ Bt,
             const float* __restrict__ bias, const float* __restrict__ res,
             void* __restrict__ Out, int M, int N, int K)
{
  constexpr int BM = 128, BN = 128, BK = 64;
  __shared__ __align__(16) __hip_bfloat16 As[BM * BK];
  __shared__ __align__(16) __hip_bfloat16 Bs[BN * BK];
  const int tid = threadIdx.x;
  const int lane = tid & 63;
  const int wave = tid >> 6;

  const int NBLK = N >> 7;
  const int bid = blockIdx.x;
  const int xcd = bid & 7;
  const int j = bid >> 3;
  const int nb = j % NBLK;
  const int mt = xcd + ((j / NBLK) << 3);
  const int m0 = mt << 7;
  const int n0 = nb << 7;

  const int wm = (wave & 1) * 64;
  const int wn = (wave >> 1) * 64;
  const int quad = lane >> 4;
  const int lrow = lane & 15;

  floatx4 acc[4][4];
  #pragma unroll
  for (int i = 0; i < 4; ++i)
    #pragma unroll
    for (int jj = 0; jj < 4; ++jj) {
      floatx4 z4 = {0.f, 0.f, 0.f, 0.f};
      acc[i][jj] = z4;
    }

  for (int k0 = 0; k0 < K; k0 += BK) {
    #pragma unroll
    for (int it = 0; it < 4; ++it) {
      int c = it * 256 + tid;
      int row = c >> 3, seg = (c & 7) ^ (row & 7);
      load_lds16(A + (size_t)(m0 + row) * K + k0 + seg * 8, As + c * 8);
    }
    #pragma unroll
    for (int it = 0; it < 4; ++it) {
      int c = it * 256 + tid;
      int row = c >> 3, seg = (c & 7) ^ (row & 7);
      load_lds16(Bt + (size_t)(n0 + row) * K + k0 + seg * 8, Bs + c * 8);
    }
    __syncthreads();

    #pragma unroll
    for (int k1 = 0; k1 < BK; k1 += 32) {
      const int s0 = k1 >> 3;   // 0 or 4
      bf16x8 a[4], b[4];
      #pragma unroll
      for (int i = 0; i < 4; ++i)
        a[i] = *reinterpret_cast<const bf16x8*>(&As[swz(wm + i * 16 + lrow, s0 + quad)]);
      #pragma unroll
      for (int i = 0; i < 4; ++i)
        b[i] = *reinterpret_cast<const bf16x8*>(&Bs[swz(wn + i * 16 + lrow, s0 + quad)]);
      #pragma unroll
      for (int mi = 0; mi < 4; ++mi)
        #pragma unroll
        for (int ni = 0; ni < 4; ++ni)
          acc[mi][ni] = __builtin_amdgcn_mfma_f32_16x16x32_bf16(a[mi], b[ni], acc[mi][ni], 0, 0, 0);
    }
    __syncthreads();
  }

  #pragma unroll
  for (int mi = 0; mi < 4; ++mi) {
    #pragma unroll
    for (int r = 0; r < 4; ++r) {
      int gm = m0 + wm + mi * 16 + quad * 4 + r;
      #pragma unroll
      for (int ni = 0; ni < 4; ++ni) {
        int gn = n0 + wn + ni * 16 + lrow;
        float v = acc[mi][ni][r];
        size_t oi = (size_t)gm * N + gn;
        if (MODE == 0) {
          ((__hip_bfloat16*)Out)[oi] = __float2bfloat16(v);
        } else if (MODE == 1) {
          ((float*)Out)[oi] = v + bias[gn] + res[oi];
        } else {
          float t = v + bias[gn];
          float g = 0.5f * t * (1.0f + erff(t * 0.70710678118654752f));
          ((__hip_bfloat16*)Out)[oi] = __float2bfloat16(g);
        }
      }
    }
  }
}

// ---------------------------------------------------------------------------
// 256x256 8-phase bf16 MFMA GEMM (T2 swizzle + T3/T4 counted vmcnt + T5
// setprio). C(M,N) = A(M,K) @ Bt(N,K)^T. 512 threads = 8 waves (2M x 4N),
// per-wave 128x64 output. BK=64 split into 2 K-halves of 32; LDS slots are
// [buf][kh] of 256x32 bf16 (16KB), 2x2 per operand = 128 KiB total.
//
// Phase order per K-tile t: P0=(ks0,mh0) P1=(ks0,mh1) P2=(ks1,mh0) P3=(ks1,mh1)
// b-fragments (ks) are register-held across the mh pair, so slot last-readers
// are: B(t,0)->P0, A(t,0)->P1, B(t,1)->P2, A(t,1)->P3. One half-tile prefetch
// per phase into the just-dead slot:
//   P0: A(t+1,1)  P1: B(t+2,0)  P2: A(t+2,0)  P3: B(t+2,1)
// Steady-state outstanding at both wait points = 5 half-tiles x 2 loads ->
// uniform s_waitcnt vmcnt(10), placed before the closing barrier of P1 and P3
// (guards P2's and next-P0's fresh ds_reads). Prologue issues 7 half-tiles;
// tail clamps the global source (dest slot is dead, data never read).
//
// LDS swizzle for [256][32] slots: 16B segment s of row r stored at
// s ^ ((r>>1)&3) -> per 16-lane group, 2 lanes/bank (free). glds stays
// lane-linear; inverse permutation applied to the global source address.
// ---------------------------------------------------------------------------
#define GBAR()    asm volatile("s_barrier" ::: "memory")
#define GWAIT10() asm volatile("s_waitcnt vmcnt(10)" ::: "memory")

template <int MODE>   // 0: bf16 out, no bias; 2: bf16 out = gelu(acc + bias)
__global__ __launch_bounds__(512, 2)
void gemm256(const __hip_bfloat16* __restrict__ A, const __hip_bfloat16* __restrict__ Bt,
             const float* __restrict__ bias, void* __restrict__ Out,
             int M, int N, int K)
{
  extern __shared__ __hip_bfloat16 lds[];   // 65536 bf16 = 128 KiB
  const int tid  = threadIdx.x;
  const int lane = tid & 63;
  const int wave = tid >> 6;
  const int wm = wave >> 2, wn = wave & 3;
  const int quad = lane >> 4, lrow = lane & 15;

  // bijective XCD swizzle (m204), then row-major (mt, nt)
  const int NBN = N >> 8;
  const int nwg = gridDim.x;
  const int bid = blockIdx.x;
  const int qq = nwg >> 3, rr = nwg & 7;
  const int xcd = bid & 7, oin = bid >> 3;
  const int wg = (xcd < rr ? xcd * (qq + 1) : rr * (qq + 1) + (xcd - rr) * qq) + oin;
  const int m0 = (wg / NBN) << 8;
  const int n0 = (wg % NBN) << 8;
  const int NT = K >> 6;

  // staging: HT = 256 rows x 32 cols; chunk c = it*512+tid holds
  // (row=c>>2, slot=c&3) with global seg = slot ^ ((row>>1)&3)
  const int srow = tid >> 2;
  const int sseg = (tid & 3) ^ ((tid >> 3) & 3);
  const __hip_bfloat16* gA = A  + (size_t)(m0 + srow) * K + sseg * 8;
  const __hip_bfloat16* gB = Bt + (size_t)(n0 + srow) * K + sseg * 8;
  const size_t gstep = (size_t)128 * K;

  __hip_bfloat16* const Abase = lds;
  __hip_bfloat16* const Bbase = lds + 32768;

  auto stageA = [&](int t, int kh) {
    int ts = t < NT ? t : NT - 1;            // clamp source, keep count uniform
    int kb = ts * 64 + kh * 32;
    __hip_bfloat16* d = Abase + ((((t & 1) << 1) | kh) * 8192) + tid * 8;
    load_lds16(gA + kb, d);
    load_lds16(gA + gstep + kb, d + 4096);
  };
  auto stageB = [&](int t, int kh) {
    int ts = t < NT ? t : NT - 1;
    int kb = ts * 64 + kh * 32;
    __hip_bfloat16* d = Bbase + ((((t & 1) << 1) | kh) * 8192) + tid * 8;
    load_lds16(gB + kb, d);
    load_lds16(gB + gstep + kb, d + 4096);
  };

  floatx4 acc[2][4][4];
  #pragma unroll
  for (int mh = 0; mh < 2; ++mh)
    #pragma unroll
    for (int mi = 0; mi < 4; ++mi)
      #pragma unroll
      for (int ni = 0; ni < 4; ++ni) {
        floatx4 z4 = {0.f, 0.f, 0.f, 0.f};
        acc[mh][mi][ni] = z4;
      }

  // ds-read offsets (elements); swizzle slot is lane-constant across frags
  // since all row bases are multiples of 16
  const int rseg = ((quad ^ ((lrow >> 1) & 3)) << 3);
  const int arow = (wm * 128 + lrow) * 32 + rseg;
  const int brow = (wn * 64 + lrow) * 32 + rseg;

  // prologue = steady-state issue history:
  // B(0,0) A(0,0) B(0,1) A(0,1) B(1,0) A(1,0) B(1,1)
  stageB(0, 0); stageA(0, 0); stageB(0, 1); stageA(0, 1);
  stageB(1, 0); stageA(1, 0); stageB(1, 1);
  GWAIT10();          // first 4 loads (B(0,0), A(0,0)) landed
  GBAR();

  bf16x8 af[4], bfr[4];
  for (int t = 0; t < NT; ++t) {
    const int par = t & 1;
    const __hip_bfloat16* As0 = Abase + ((par << 1) | 0) * 8192;
    const __hip_bfloat16* As1 = Abase + ((par << 1) | 1) * 8192;
    const __hip_bfloat16* Bs0 = Bbase + ((par << 1) | 0) * 8192;
    const __hip_bfloat16* Bs1 = Bbase + ((par << 1) | 1) * 8192;

    // ---- P0: (ks=0, mh=0) : 8 ds_read, stage A(t+1,1) ----
    #pragma unroll
    for (int ni = 0; ni < 4; ++ni)
      bfr[ni] = *reinterpret_cast<const bf16x8*>(Bs0 + brow + ni * 512);
    #pragma unroll
    for (int mi = 0; mi < 4; ++mi)
      af[mi] = *reinterpret_cast<const bf16x8*>(As0 + arow + mi * 512);
    stageA(t + 1, 1);
    GBAR();
    __builtin_amdgcn_s_setprio(1);
    #pragma unroll
    for (int mi = 0; mi < 4; ++mi)
      #pragma unroll
      for (int ni = 0; ni < 4; ++ni)
        acc[0][mi][ni] = __builtin_amdgcn_mfma_f32_16x16x32_bf16(af[mi], bfr[ni], acc[0][mi][ni], 0, 0, 0);
    __builtin_amdgcn_s_setprio(0);
    GBAR();

    // ---- P1: (ks=0, mh=1) : 4 ds_read (b reused), stage B(t+2,0) ----
    #pragma unroll
    for (int mi = 0; mi < 4; ++mi)
      af[mi] = *reinterpret_cast<const bf16x8*>(As0 + arow + 2048 + mi * 512);
    stageB(t + 2, 0);
    GBAR();
    __builtin_amdgcn_s_setprio(1);
    #pragma unroll
    for (int mi = 0; mi < 4; ++mi)
      #pragma unroll
      for (int ni = 0; ni < 4; ++ni)
        acc[1][mi][ni] = __builtin_amdgcn_mfma_f32_16x16x32_bf16(af[mi], bfr[ni], acc[1][mi][ni], 0, 0, 0);
    __builtin_amdgcn_s_setprio(0);
    GWAIT10();        // guards P2's fresh reads (A(t,1), B(t,1))
    GBAR();

    // ---- P2: (ks=1, mh=0) : 8 ds_read, stage A(t+2,0) ----
    #pragma unroll
    for (int ni = 0; ni < 4; ++ni)
      bfr[ni] = *reinterpret_cast<const bf16x8*>(Bs1 + brow + ni * 512);
    #pragma unroll
    for (int mi = 0; mi < 4; ++mi)
      af[mi] = *reinterpret_cast<const bf16x8*>(As1 + arow + mi * 512);
    stageA(t + 2, 0);
    GBAR();
    __builtin_amdgcn_s_setprio(1);
    #pragma unroll
    for (int mi = 0; mi < 4; ++mi)
      #pragma unroll
      for (int ni = 0; ni < 4; ++ni)
        acc[0][mi][ni] = __builtin_amdgcn_mfma_f32_16x16x32_bf16(af[mi], bfr[ni], acc[0][mi][ni], 0, 0, 0);
    __builtin_amdgcn_s_setprio(0);
    GBAR();

    // ---- P3: (ks=1, mh=1) : 4 ds_read, stage B(t+2,1) ----
    #pragma unroll
    for (int mi = 0; mi < 4; ++mi)
      af[mi] = *reinterpret_cast<const bf16x8*>(As1 + arow + 2048 + mi * 512);
    stageB(t + 2, 1);
    GBAR();
    __builtin_amdgcn_s_setprio(1);
    #pragma unroll
    for (int mi = 0; mi < 4; ++mi)
      #pragma unroll
      for (int ni = 0; ni < 4; ++ni)
        acc[1][mi][ni] = __builtin_amdgcn_mfma_f32_16x16x32_bf16(af[mi], bfr[ni], acc[1][mi][ni], 0, 0, 0);
    __builtin_amdgcn_s_setprio(0);
    GWAIT10();        // guards next tile P0's fresh reads (A(t+1,0), B(t+1,0))
    GBAR();
  }

  // epilogue
  const int cm0 = m0 + wm * 128 + quad * 4;
  const int cn0 = n0 + wn * 64 + lrow;
  #pragma unroll
  for (int mh = 0; mh < 2; ++mh)
    #pragma unroll
    for (int mi = 0; mi < 4; ++mi)
      #pragma unroll
      for (int r = 0; r < 4; ++r) {
        const int gm = cm0 + mh * 64 + mi * 16 + r;
        #pragma unroll
        for (int ni = 0; ni < 4; ++ni) {
          const int gn = cn0 + ni * 16;
          float v = acc[mh][mi][ni][r];
          size_t oi = (size_t)gm * N + gn;
          if (MODE == 0) {
            ((__hip_bfloat16*)Out)[oi] = __float2bfloat16(v);
          } else {
            float tt = v + bias[gn];
            float g = 0.5f * tt * (1.0f + erff(tt * 0.70710678118654752f));
            ((__hip_bfloat16*)Out)[oi] = __float2bfloat16(g);
          }
        }
      }
}

// ---------------------------------------------------------------------------
// Pair-balanced MFMA flash attention with XOR-swizzled LDS + reg prefetch.
// ---------------------------------------------------------------------------
__global__ __launch_bounds__(256, 2)
void attn_pair(const __hip_bfloat16* __restrict__ qkv, __hip_bfloat16* __restrict__ o)
{
  const int p = blockIdx.x;            // 0..3
  const int h = blockIdx.y, b = blockIdx.z;
  const int t0 = p, t1 = 7 - p;

  __shared__ __align__(16) __hip_bfloat16 Qs[2][64 * 64];
  __shared__ __align__(16) __hip_bfloat16 Ks[64 * 64];
  __shared__ __align__(16) __hip_bfloat16 Vt[64 * 64];   // (dh, key), swizzled
  __shared__ __align__(16) __hip_bfloat16 Ps[4][16 * 64];

  const int tid = threadIdx.x, lane = tid & 63, wave = tid >> 6;
  const int quad = lane >> 4, col = lane & 15;
  const size_t base = ((size_t)b * Ss) * 1536 + (size_t)h * 64;

  // stage Q for both tiles (swizzled)
  #pragma unroll
  for (int t = 0; t < 2; ++t) {
    const int tq = t ? t1 : t0;
    #pragma unroll
    for (int it = 0; it < 2; ++it) {
      int c = it * 256 + tid;
      int row = c >> 3, seg = c & 7;
      bf16x8 q8 = *reinterpret_cast<const bf16x8*>(
          qkv + base + (size_t)(tq * 64 + row) * 1536 + seg * 8);
      *reinterpret_cast<bf16x8*>(&Qs[t][swz(row, seg)]) = q8;
    }
  }

  bf16x8 kreg[2], vreg[2];
  auto load_kv = [&](int c0) {
    #pragma unroll
    for (int it = 0; it < 2; ++it) {
      int c = it * 256 + tid;
      kreg[it] = *reinterpret_cast<const bf16x8*>(
          qkv + base + 512 + (size_t)(c0 * 64 + (c >> 3)) * 1536 + (c & 7) * 8);
    }
    #pragma unroll
    for (int it = 0; it < 2; ++it) {
      int row = tid & 63, seg = it * 4 + wave;
      vreg[it] = *reinterpret_cast<const bf16x8*>(
          qkv + base + 1024 + (size_t)(c0 * 64 + row) * 1536 + seg * 8);
    }
  };
  auto store_kv = [&]() {
    #pragma unroll
    for (int it = 0; it < 2; ++it) {
      int c = it * 256 + tid;
      *reinterpret_cast<bf16x8*>(&Ks[swz(c >> 3, c & 7)]) = kreg[it];
    }
    #pragma unroll
    for (int it = 0; it < 2; ++it) {
      int row = tid & 63, seg = it * 4 + wave;
      union { bf16x8 v; __hip_bfloat16 e[8]; } u; u.v = vreg[it];
      #pragma unroll
      for (int j = 0; j < 8; ++j) {
        int d = seg * 8 + j;
        Vt[d * 64 + ((((row >> 3)) ^ (d & 7)) << 3) + (row & 7)] = u.e[j];
      }
    }
  };

  float  mrow[2][4], lsum[2][4];
  floatx4 accO[2][4];
  #pragma unroll
  for (int t = 0; t < 2; ++t)
    #pragma unroll
    for (int r = 0; r < 4; ++r) {
      mrow[t][r] = -1e30f; lsum[t][r] = 0.f;
      floatx4 z4 = {0.f, 0.f, 0.f, 0.f};
      accO[t][r] = z4;
    }

  auto compute_tile = [&](const __hip_bfloat16* Qt, int tq, int c,
                          float* mr, float* ls, floatx4* aO) {
    floatx4 accS[4];
    #pragma unroll
    for (int i = 0; i < 4; ++i) { floatx4 z4 = {0.f,0.f,0.f,0.f}; accS[i] = z4; }
    const int m = wave * 16 + col;
    #pragma unroll
    for (int kc = 0; kc < 2; ++kc) {
      bf16x8 aq = *reinterpret_cast<const bf16x8*>(&Qt[swz(m, kc * 4 + quad)]);
      #pragma unroll
      for (int ni = 0; ni < 4; ++ni) {
        bf16x8 bk = *reinterpret_cast<const bf16x8*>(&Ks[swz(ni * 16 + col, kc * 4 + quad)]);
        accS[ni] = __builtin_amdgcn_mfma_f32_16x16x32_bf16(aq, bk, accS[ni], 0, 0, 0);
      }
    }

    const bool diag = (c == tq);
    float sc[4][4];
    #pragma unroll
    for (int ni = 0; ni < 4; ++ni)
      #pragma unroll
      for (int r = 0; r < 4; ++r) {
        float s = accS[ni][r] * 0.125f;
        if (diag && (ni * 16 + col) > (wave * 16 + quad * 4 + r)) s = -1e30f;
        sc[ni][r] = s;
      }

    #pragma unroll
    for (int r = 0; r < 4; ++r) {
      float cm = fmaxf(fmaxf(sc[0][r], sc[1][r]), fmaxf(sc[2][r], sc[3][r]));
      #pragma unroll
      for (int off = 1; off < 16; off <<= 1) cm = fmaxf(cm, __shfl_xor(cm, off));
      float mnew = fmaxf(mr[r], cm);
      float alpha = __expf(mr[r] - mnew);
      mr[r] = mnew;
      float ps = 0.f;
      #pragma unroll
      for (int ni = 0; ni < 4; ++ni) {
        float pv = __expf(sc[ni][r] - mnew);
        sc[ni][r] = pv;
        ps += pv;
      }
      #pragma unroll
      for (int off = 1; off < 16; off <<= 1) ps += __shfl_xor(ps, off);
      ls[r] = ls[r] * alpha + ps;
      #pragma unroll
      for (int ni = 0; ni < 4; ++ni) aO[ni][r] *= alpha;
    }

    #pragma unroll
    for (int ni = 0; ni < 4; ++ni)
      #pragma unroll
      for (int r = 0; r < 4; ++r) {
        int prow = quad * 4 + r;
        int pseg = ni * 2 + (col >> 3);
        Ps[wave][prow * 64 + ((pseg ^ (prow & 7)) << 3) + (col & 7)] =
            __float2bfloat16(sc[ni][r]);
      }

    #pragma unroll
    for (int kc = 0; kc < 2; ++kc) {
      bf16x8 ap = *reinterpret_cast<const bf16x8*>(&Ps[wave][swz(col, kc * 4 + quad)]);
      #pragma unroll
      for (int ni = 0; ni < 4; ++ni) {
        bf16x8 bv = *reinterpret_cast<const bf16x8*>(&Vt[swz(ni * 16 + col, kc * 4 + quad)]);
        aO[ni] = __builtin_amdgcn_mfma_f32_16x16x32_bf16(ap, bv, aO[ni], 0, 0, 0);
      }
    }
  };

  load_kv(0);
  for (int c = 0; c <= t1; ++c) {
    __syncthreads();
    store_kv();
    __syncthreads();
    if (c < t1) load_kv(c + 1);
    compute_tile(Qs[1], t1, c, mrow[1], lsum[1], accO[1]);
    if (c <= t0) compute_tile(Qs[0], t0, c, mrow[0], lsum[0], accO[0]);
  }

  #pragma unroll
  for (int t = 0; t < 2; ++t) {
    const int tq = t ? t1 : t0;
    float inv[4];
    #pragma unroll
    for (int r = 0; r < 4; ++r) inv[r] = 1.f / lsum[t][r];
    #pragma unroll
    for (int ni = 0; ni < 4; ++ni)
      #pragma unroll
      for (int r = 0; r < 4; ++r) {
        int qg = tq * 64 + wave * 16 + quad * 4 + r;
        o[((size_t)b * Ss + qg) * INNERi + h * 64 + ni * 16 + col] =
            __float2bfloat16(accO[t][ni][r] * inv[r]);
      }
  }
}

// ---------------------------------------------------------------------------
// Epilogue gather: out[b,d,sp] = x[b, 255+sp, d]
// ---------------------------------------------------------------------------
__global__ void epilogue_kernel(const float* __restrict__ x, float* __restrict__ out)
{
  int idx = blockIdx.x * 256 + threadIdx.x;    // over B*D*256
  int sp = idx & 255;
  int bd = idx >> 8;
  int b = bd >> 9, d = bd & 511;
  out[idx] = x[((size_t)b * Ss + (NCc - 1) + sp) * Dd + d];
}

// ---------------------------------------------------------------------------
extern "C" void kernel_launch(void* const* d_in, const int* in_sizes, int n_in,
                              void* d_out, int out_size, void* d_ws, size_t ws_size,
                              hipStream_t stream)
{
  const float* z       = (const float*)d_in[0];
  const float* slots   = (const float*)d_in[1];
  const float* pos_emb = (const float*)d_in[2];
  const float* spos    = (const float*)d_in[3];
  const float* norm_w  = (const float*)d_in[4];
  const float* norm_b  = (const float*)d_in[5];
  const float* ln1_w   = (const float*)d_in[6];
  const float* ln1_b   = (const float*)d_in[7];
  const float* qkv_w   = (const float*)d_in[8];
  const float* out_w   = (const float*)d_in[9];
  const float* out_b   = (const float*)d_in[10];
  const float* ln2_w   = (const float*)d_in[11];
  const float* ln2_b   = (const float*)d_in[12];
  const float* mlp_w1  = (const float*)d_in[13];
  const float* mlp_b1  = (const float*)d_in[14];
  const float* mlp_w2  = (const float*)d_in[15];
  const float* mlp_b2  = (const float*)d_in[16];

  char* ws = (char*)d_ws;
  float*          xbuf = (float*)ws;
  __hip_bfloat16* ybuf = (__hip_bfloat16*)(ws + 33554432);
  __hip_bfloat16* qkvb = (__hip_bfloat16*)(ws + 50331648);
  __hip_bfloat16* obuf = (__hip_bfloat16*)(ws + 100663296);
  __hip_bfloat16* hbuf = (__hip_bfloat16*)(ws + 50331648);
  __hip_bfloat16* wT   = (__hip_bfloat16*)(ws + 117440512);

  const size_t WL = 3145728;

  // allow 128 KiB dynamic LDS for the 256^2 8-phase GEMMs
  hipFuncSetAttribute(reinterpret_cast<const void*>(&gemm256<0>),
                      hipFuncAttributeMaxDynamicSharedMemorySize, 131072);
  hipFuncSetAttribute(reinterpret_cast<const void*>(&gemm256<2>),
                      hipFuncAttributeMaxDynamicSharedMemorySize, 131072);

  dim3 tb(32, 8);
  transpose_w<<<dim3(1536 / 32, 512 / 32, 8), tb, 0, stream>>>(qkv_w,  wT + 0,       512, 1536, (size_t)512 * 1536, WL);
  transpose_w<<<dim3(512 / 32,  512 / 32, 8), tb, 0, stream>>>(out_w,  wT + 786432,  512, 512,  (size_t)512 * 512,  WL);
  transpose_w<<<dim3(2048 / 32, 512 / 32, 8), tb, 0, stream>>>(mlp_w1, wT + 1048576, 512, 2048, (size_t)512 * 2048, WL);
  transpose_w<<<dim3(512 / 32, 2048 / 32, 8), tb, 0, stream>>>(mlp_w2, wT + 2097152, 2048, 512, (size_t)2048 * 512, WL);

  prologue_kernel<<<Mrows, 64, 0, stream>>>(z, slots, pos_emb, spos, norm_w, norm_b, xbuf);

  for (int i = 0; i < 8; ++i) {
    const __hip_bfloat16* qkvT = wT + (size_t)i * WL;
    const __hip_bfloat16* outT = wT + (size_t)i * WL + 786432;
    const __hip_bfloat16* w1T  = wT + (size_t)i * WL + 1048576;
    const __hip_bfloat16* w2T  = wT + (size_t)i * WL + 2097152;

    ln_kernel<<<Mrows / 4, 256, 0, stream>>>(xbuf, ln1_w + i * Dd, ln1_b + i * Dd, ybuf);
    gemm256<0><<<dim3((1536 / 256) * (Mrows / 256)), 512, 131072, stream>>>(
        ybuf, qkvT, nullptr, qkvb, Mrows, 1536, 512);
    attn_pair<<<dim3(4, NHh, Bb), 256, 0, stream>>>(qkvb, obuf);
    gemm_bt<1><<<dim3((512 / 128) * (Mrows / 128)), 256, 0, stream>>>(
        obuf, outT, out_b + i * Dd, xbuf, xbuf, Mrows, 512, 512);
    ln_kernel<<<Mrows / 4, 256, 0, stream>>>(xbuf, ln2_w + i * Dd, ln2_b + i * Dd, ybuf);
    gemm256<2><<<dim3((2048 / 256) * (Mrows / 256)), 512, 131072, stream>>>(
        ybuf, w1T, mlp_b1 + i * MLPm, hbuf, Mrows, 2048, 512);
    gemm_bt<1><<<dim3((512 / 128) * (Mrows / 128)), 256, 0, stream>>>(
        hbuf, w2T, mlp_b2 + i * Dd, xbuf, xbuf, Mrows, 512, 2048);
  }

  epilogue_kernel<<<(Bb * Dd * 256) / 256, 256, 0, stream>>>(xbuf, (float*)d_out);
}

// Round 2
// 1960.389 us; speedup vs baseline: 1.0769x; 1.0769x over previous
//
#include <hip/hip_runtime.h>
#include <hip/hip_bf16.h>
#include <math.h>

// Problem constants
#define Bb 32
#define Dd 512
#define Ss 512      // NC + Hs*Ws
#define NHh 8
#define DHh 64
#define MLPm 2048
#define NCc 256
#define INNERi 512
#define Mrows (Bb*Ss)   // 16384

typedef __bf16 bf16x8 __attribute__((ext_vector_type(8)));
typedef float floatx4 __attribute__((ext_vector_type(4)));

__device__ __forceinline__ void load_lds16(const void* g, void* l) {
  __builtin_amdgcn_global_load_lds(
      (__attribute__((address_space(1))) void*)(g),
      (__attribute__((address_space(3))) void*)(l), 16, 0, 0);
}

// XOR-swizzled LDS addressing for 64-elem bf16 rows: logical (row, seg8)
// stored at row*64 + ((seg ^ (row&7))<<3). b128 frag reads spread banks.
__device__ __forceinline__ int swz(int row, int seg) {
  return row * 64 + (((seg) ^ (row & 7)) << 3);
}

// ---------------------------------------------------------------------------
// Tiled transpose + fp32->bf16 downcast: in (K,N) fp32 -> out (N,K) bf16
// ---------------------------------------------------------------------------
__global__ void transpose_w(const float* __restrict__ in, __hip_bfloat16* __restrict__ out,
                            int K, int N, size_t in_ls, size_t out_ls)
{
  __shared__ float tile[32][33];
  in  += (size_t)blockIdx.z * in_ls;
  out += (size_t)blockIdx.z * out_ls;
  int n0 = blockIdx.x * 32, k0 = blockIdx.y * 32;
  int tx = threadIdx.x;
  #pragma unroll
  for (int i = threadIdx.y; i < 32; i += 8)
    tile[i][tx] = in[(size_t)(k0 + i) * N + n0 + tx];
  __syncthreads();
  #pragma unroll
  for (int i = threadIdx.y; i < 32; i += 8)
    out[(size_t)(n0 + i) * K + k0 + tx] = __float2bfloat16(tile[tx][i]);
}

// ---------------------------------------------------------------------------
// Prologue: build x[b,s,:] (slots+slot_pos | z^T+pos), then LayerNorm(norm_w/b)
// ---------------------------------------------------------------------------
__global__ void prologue_kernel(const float* __restrict__ z, const float* __restrict__ slots,
                                const float* __restrict__ pos, const float* __restrict__ spos,
                                const float* __restrict__ nw, const float* __restrict__ nb,
                                float* __restrict__ x)
{
  int row = blockIdx.x;            // b*S + s
  int b = row >> 9, s = row & 511;
  int lane = threadIdx.x;
  float v[8];
  float sum = 0.f;
  #pragma unroll
  for (int j = 0; j < 8; ++j) {
    int d = lane + j * 64;
    float t;
    if (s < NCc) t = slots[((size_t)b * NCc + s) * Dd + d] + spos[(size_t)s * Dd + d];
    else {
      int sp = s - NCc;
      t = z[((size_t)b * Dd + d) * 256 + sp] + pos[(size_t)sp * Dd + d];
    }
    v[j] = t; sum += t;
  }
  #pragma unroll
  for (int o = 32; o; o >>= 1) sum += __shfl_xor(sum, o);
  float mean = sum * (1.f / Dd);
  float vs = 0.f;
  #pragma unroll
  for (int j = 0; j < 8; ++j) { float d = v[j] - mean; vs += d * d; }
  #pragma unroll
  for (int o = 32; o; o >>= 1) vs += __shfl_xor(vs, o);
  float rs = rsqrtf(vs * (1.f / Dd) + 1e-5f);
  #pragma unroll
  for (int j = 0; j < 8; ++j) {
    int d = lane + j * 64;
    x[(size_t)row * Dd + d] = (v[j] - mean) * rs * nw[d] + nb[d];
  }
}

// ---------------------------------------------------------------------------
// LayerNorm: x fp32 (rows,512) -> y bf16
// ---------------------------------------------------------------------------
__global__ void ln_kernel(const float* __restrict__ x, const float* __restrict__ w,
                          const float* __restrict__ b, __hip_bfloat16* __restrict__ y)
{
  int row = blockIdx.x * 4 + (threadIdx.x >> 6);
  int lane = threadIdx.x & 63;
  const float* xr = x + (size_t)row * Dd;
  float v[8];
  float sum = 0.f;
  #pragma unroll
  for (int j = 0; j < 8; ++j) { v[j] = xr[lane + j * 64]; sum += v[j]; }
  #pragma unroll
  for (int o = 32; o; o >>= 1) sum += __shfl_xor(sum, o);
  float mean = sum * (1.f / Dd);
  float vs = 0.f;
  #pragma unroll
  for (int j = 0; j < 8; ++j) { float d = v[j] - mean; vs += d * d; }
  #pragma unroll
  for (int o = 32; o; o >>= 1) vs += __shfl_xor(vs, o);
  float rs = rsqrtf(vs * (1.f / Dd) + 1e-5f);
  #pragma unroll
  for (int j = 0; j < 8; ++j) {
    int d = lane + j * 64;
    y[(size_t)row * Dd + d] = __float2bfloat16((v[j] - mean) * rs * w[d] + b[d]);
  }
}

// ---------------------------------------------------------------------------
// bf16 MFMA GEMM (128x128 tile, m97 structure): C(M,N) = A(M,K) @ Bt(N,K)^T
// Kept for the N=512 GEMMs (out-proj, mlp2).
// ---------------------------------------------------------------------------
template <int MODE>
__global__ __launch_bounds__(256, 2)
void gemm_bt(const __hip_bfloat16* __restrict__ A, const __hip_bfloat16* __restrict__ Bt,
             const float* __restrict__ bias, const float* __restrict__ res,
             void* __restrict__ Out, int M, int N, int K)
{
  constexpr int BM = 128, BN = 128, BK = 64;
  __shared__ __align__(16) __hip_bfloat16 As[BM * BK];
  __shared__ __align__(16) __hip_bfloat16 Bs[BN * BK];
  const int tid = threadIdx.x;
  const int lane = tid & 63;
  const int wave = tid >> 6;

  const int NBLK = N >> 7;
  const int bid = blockIdx.x;
  const int xcd = bid & 7;
  const int j = bid >> 3;
  const int nb = j % NBLK;
  const int mt = xcd + ((j / NBLK) << 3);
  const int m0 = mt << 7;
  const int n0 = nb << 7;

  const int wm = (wave & 1) * 64;
  const int wn = (wave >> 1) * 64;
  const int quad = lane >> 4;
  const int lrow = lane & 15;

  floatx4 acc[4][4];
  #pragma unroll
  for (int i = 0; i < 4; ++i)
    #pragma unroll
    for (int jj = 0; jj < 4; ++jj) {
      floatx4 z4 = {0.f, 0.f, 0.f, 0.f};
      acc[i][jj] = z4;
    }

  for (int k0 = 0; k0 < K; k0 += BK) {
    #pragma unroll
    for (int it = 0; it < 4; ++it) {
      int c = it * 256 + tid;
      int row = c >> 3, seg = (c & 7) ^ (row & 7);
      load_lds16(A + (size_t)(m0 + row) * K + k0 + seg * 8, As + c * 8);
    }
    #pragma unroll
    for (int it = 0; it < 4; ++it) {
      int c = it * 256 + tid;
      int row = c >> 3, seg = (c & 7) ^ (row & 7);
      load_lds16(Bt + (size_t)(n0 + row) * K + k0 + seg * 8, Bs + c * 8);
    }
    __syncthreads();

    #pragma unroll
    for (int k1 = 0; k1 < BK; k1 += 32) {
      const int s0 = k1 >> 3;   // 0 or 4
      bf16x8 a[4], b[4];
      #pragma unroll
      for (int i = 0; i < 4; ++i)
        a[i] = *reinterpret_cast<const bf16x8*>(&As[swz(wm + i * 16 + lrow, s0 + quad)]);
      #pragma unroll
      for (int i = 0; i < 4; ++i)
        b[i] = *reinterpret_cast<const bf16x8*>(&Bs[swz(wn + i * 16 + lrow, s0 + quad)]);
      #pragma unroll
      for (int mi = 0; mi < 4; ++mi)
        #pragma unroll
        for (int ni = 0; ni < 4; ++ni)
          acc[mi][ni] = __builtin_amdgcn_mfma_f32_16x16x32_bf16(a[mi], b[ni], acc[mi][ni], 0, 0, 0);
    }
    __syncthreads();
  }

  #pragma unroll
  for (int mi = 0; mi < 4; ++mi) {
    #pragma unroll
    for (int r = 0; r < 4; ++r) {
      int gm = m0 + wm + mi * 16 + quad * 4 + r;
      #pragma unroll
      for (int ni = 0; ni < 4; ++ni) {
        int gn = n0 + wn + ni * 16 + lrow;
        float v = acc[mi][ni][r];
        size_t oi = (size_t)gm * N + gn;
        if (MODE == 0) {
          ((__hip_bfloat16*)Out)[oi] = __float2bfloat16(v);
        } else if (MODE == 1) {
          ((float*)Out)[oi] = v + bias[gn] + res[oi];
        } else {
          float t = v + bias[gn];
          float g = 0.5f * t * (1.0f + erff(t * 0.70710678118654752f));
          ((__hip_bfloat16*)Out)[oi] = __float2bfloat16(g);
        }
      }
    }
  }
}

// ---------------------------------------------------------------------------
// 256x256 8-phase bf16 MFMA GEMM. Round-2 fix: the round-1 version used
// plain C++ LDS reads; the compiler models global_load_lds as an LDS write
// it cannot disambiguate from those reads, so it inserted vmcnt(0) drains
// every phase (MfmaUtil 10%, ~2475 cyc/phase = one load latency per phase).
// Now ALL K-loop LDS reads are inline-asm ds_read_b128 on raw 32-bit LDS
// addresses (invisible to the dependency tracker), with explicit
// s_waitcnt lgkmcnt(0) + sched_barrier(0) before each MFMA cluster
// (rule #18). The counted-vmcnt ledger is now load-bearing:
//   phase stages: P0->A(t+1,1) P1->B(t+2,0) P2->A(t+2,0) P3->B(t+2,1)
//   steady-state outstanding at the two wait points = 5 half-tiles x 2
//   loads -> s_waitcnt vmcnt(10) before the closing barrier of P1 and P3.
//   Audit: every consumed slot's loads are covered with equality.
// ---------------------------------------------------------------------------
#define GBAR()    asm volatile("s_barrier" ::: "memory")
#define GWAIT10() asm volatile("s_waitcnt vmcnt(10)" ::: "memory")
#define GWAIT0()  asm volatile("s_waitcnt vmcnt(0)" ::: "memory")
#define LGKM0()   do { asm volatile("s_waitcnt lgkmcnt(0)" ::: "memory"); \
                       __builtin_amdgcn_sched_barrier(0); } while (0)
#define DSR0(d,a)  asm volatile("ds_read_b128 %0, %1"             : "=v"(d) : "v"(a))
#define DSR1(d,a)  asm volatile("ds_read_b128 %0, %1 offset:1024" : "=v"(d) : "v"(a))
#define DSR2(d,a)  asm volatile("ds_read_b128 %0, %1 offset:2048" : "=v"(d) : "v"(a))
#define DSR3(d,a)  asm volatile("ds_read_b128 %0, %1 offset:3072" : "=v"(d) : "v"(a))

template <int MODE>   // 0: bf16 out, no bias; 2: bf16 out = gelu(acc + bias)
__global__ __launch_bounds__(512, 2)
void gemm256(const __hip_bfloat16* __restrict__ A, const __hip_bfloat16* __restrict__ Bt,
             const float* __restrict__ bias, void* __restrict__ Out,
             int M, int N, int K)
{
  extern __shared__ __hip_bfloat16 lds[];   // 65536 bf16 = 128 KiB
  const int tid  = threadIdx.x;
  const int lane = tid & 63;
  const int wave = tid >> 6;
  const int wm = wave >> 2, wn = wave & 3;
  const int quad = lane >> 4, lrow = lane & 15;

  // bijective XCD swizzle (m204), then row-major (mt, nt)
  const int NBN = N >> 8;
  const int nwg = gridDim.x;
  const int bid = blockIdx.x;
  const int qq = nwg >> 3, rr = nwg & 7;
  const int xcd = bid & 7, oin = bid >> 3;
  const int wg = (xcd < rr ? xcd * (qq + 1) : rr * (qq + 1) + (xcd - rr) * qq) + oin;
  const int m0 = (wg / NBN) << 8;
  const int n0 = (wg % NBN) << 8;
  const int NT = K >> 6;

  // staging: slot = 256 rows x 32 cols bf16 (16 KB) via 2x load_lds16/thread;
  // global seg XOR-permuted so lane-linear LDS lands swizzled.
  const int srow = tid >> 2;
  const int sseg = (tid & 3) ^ ((tid >> 3) & 3);
  const __hip_bfloat16* gA = A  + (size_t)(m0 + srow) * K + sseg * 8;
  const __hip_bfloat16* gB = Bt + (size_t)(n0 + srow) * K + sseg * 8;
  const size_t gstep = (size_t)128 * K;

  __hip_bfloat16* const Abase = lds;
  __hip_bfloat16* const Bbase = lds + 32768;

  auto stageA = [&](int t, int kh) {
    int ts = t < NT ? t : NT - 1;            // clamp source, keep count uniform
    int kb = ts * 64 + kh * 32;
    __hip_bfloat16* d = Abase + ((((t & 1) << 1) | kh) * 8192) + tid * 8;
    load_lds16(gA + kb, d);
    load_lds16(gA + gstep + kb, d + 4096);
  };
  auto stageB = [&](int t, int kh) {
    int ts = t < NT ? t : NT - 1;
    int kb = ts * 64 + kh * 32;
    __hip_bfloat16* d = Bbase + ((((t & 1) << 1) | kh) * 8192) + tid * 8;
    load_lds16(gB + kb, d);
    load_lds16(gB + gstep + kb, d + 4096);
  };

  floatx4 acc[2][4][4];
  #pragma unroll
  for (int mh = 0; mh < 2; ++mh)
    #pragma unroll
    for (int mi = 0; mi < 4; ++mi)
      #pragma unroll
      for (int ni = 0; ni < 4; ++ni) {
        floatx4 z4 = {0.f, 0.f, 0.f, 0.f};
        acc[mh][mi][ni] = z4;
      }

  // raw 32-bit LDS byte addresses for asm ds_read
  const uint32_t ldsA = (uint32_t)(size_t)(__attribute__((address_space(3))) void*)Abase;
  const uint32_t ldsB = (uint32_t)(size_t)(__attribute__((address_space(3))) void*)Bbase;
  const uint32_t rsegb = (uint32_t)((quad ^ ((lrow >> 1) & 3)) << 4);
  const uint32_t arow_b = (uint32_t)((wm * 128 + lrow) * 64) + rsegb;
  const uint32_t brow_b = (uint32_t)((wn * 64 + lrow) * 64) + rsegb;

  // prologue = steady-state issue history:
  // B(0,0) A(0,0) B(0,1) A(0,1) B(1,0) A(1,0) B(1,1)
  stageB(0, 0); stageA(0, 0); stageB(0, 1); stageA(0, 1);
  stageB(1, 0); stageA(1, 0); stageB(1, 1);
  GWAIT10();          // first 4 loads (B(0,0), A(0,0)) landed
  GBAR();

  bf16x8 af[4], bfr[4];
  for (int t = 0; t < NT; ++t) {
    const uint32_t aS = ldsA + (uint32_t)((t & 1) * 32768);
    const uint32_t bS = ldsB + (uint32_t)((t & 1) * 32768);
    const uint32_t a0 = aS + arow_b;            // A(t,0), mh=0
    const uint32_t b0 = bS + brow_b;            // B(t,0)
    const uint32_t a1 = aS + 16384 + arow_b;    // A(t,1), mh=0
    const uint32_t b1 = bS + 16384 + brow_b;    // B(t,1)

    // ---- P0: (ks=0, mh=0) ----
    DSR0(bfr[0], b0); DSR1(bfr[1], b0); DSR2(bfr[2], b0); DSR3(bfr[3], b0);
    DSR0(af[0], a0);  DSR1(af[1], a0);  DSR2(af[2], a0);  DSR3(af[3], a0);
    stageA(t + 1, 1);
    GBAR();
    LGKM0();
    __builtin_amdgcn_s_setprio(1);
    #pragma unroll
    for (int mi = 0; mi < 4; ++mi)
      #pragma unroll
      for (int ni = 0; ni < 4; ++ni)
        acc[0][mi][ni] = __builtin_amdgcn_mfma_f32_16x16x32_bf16(af[mi], bfr[ni], acc[0][mi][ni], 0, 0, 0);
    __builtin_amdgcn_s_setprio(0);
    GBAR();

    // ---- P1: (ks=0, mh=1) : b-frags reused ----
    DSR0(af[0], a0 + 4096); DSR1(af[1], a0 + 4096);
    DSR2(af[2], a0 + 4096); DSR3(af[3], a0 + 4096);
    stageB(t + 2, 0);
    GBAR();
    LGKM0();
    __builtin_amdgcn_s_setprio(1);
    #pragma unroll
    for (int mi = 0; mi < 4; ++mi)
      #pragma unroll
      for (int ni = 0; ni < 4; ++ni)
        acc[1][mi][ni] = __builtin_amdgcn_mfma_f32_16x16x32_bf16(af[mi], bfr[ni], acc[1][mi][ni], 0, 0, 0);
    __builtin_amdgcn_s_setprio(0);
    GWAIT10();        // guards P2's fresh reads (A(t,1), B(t,1))
    GBAR();

    // ---- P2: (ks=1, mh=0) ----
    DSR0(bfr[0], b1); DSR1(bfr[1], b1); DSR2(bfr[2], b1); DSR3(bfr[3], b1);
    DSR0(af[0], a1);  DSR1(af[1], a1);  DSR2(af[2], a1);  DSR3(af[3], a1);
    stageA(t + 2, 0);
    GBAR();
    LGKM0();
    __builtin_amdgcn_s_setprio(1);
    #pragma unroll
    for (int mi = 0; mi < 4; ++mi)
      #pragma unroll
      for (int ni = 0; ni < 4; ++ni)
        acc[0][mi][ni] = __builtin_amdgcn_mfma_f32_16x16x32_bf16(af[mi], bfr[ni], acc[0][mi][ni], 0, 0, 0);
    __builtin_amdgcn_s_setprio(0);
    GBAR();

    // ---- P3: (ks=1, mh=1) ----
    DSR0(af[0], a1 + 4096); DSR1(af[1], a1 + 4096);
    DSR2(af[2], a1 + 4096); DSR3(af[3], a1 + 4096);
    stageB(t + 2, 1);
    GBAR();
    LGKM0();
    __builtin_amdgcn_s_setprio(1);
    #pragma unroll
    for (int mi = 0; mi < 4; ++mi)
      #pragma unroll
      for (int ni = 0; ni < 4; ++ni)
        acc[1][mi][ni] = __builtin_amdgcn_mfma_f32_16x16x32_bf16(af[mi], bfr[ni], acc[1][mi][ni], 0, 0, 0);
    __builtin_amdgcn_s_setprio(0);
    GWAIT10();        // guards next tile P0's fresh reads (A(t+1,0), B(t+1,0))
    GBAR();
  }

  GWAIT0();   // drain in-flight glds before block exit (LDS gets reassigned)

  // epilogue
  const int cm0 = m0 + wm * 128 + quad * 4;
  const int cn0 = n0 + wn * 64 + lrow;
  #pragma unroll
  for (int mh = 0; mh < 2; ++mh)
    #pragma unroll
    for (int mi = 0; mi < 4; ++mi)
      #pragma unroll
      for (int r = 0; r < 4; ++r) {
        const int gm = cm0 + mh * 64 + mi * 16 + r;
        #pragma unroll
        for (int ni = 0; ni < 4; ++ni) {
          const int gn = cn0 + ni * 16;
          float v = acc[mh][mi][ni][r];
          size_t oi = (size_t)gm * N + gn;
          if (MODE == 0) {
            ((__hip_bfloat16*)Out)[oi] = __float2bfloat16(v);
          } else {
            float tt = v + bias[gn];
            float g = 0.5f * tt * (1.0f + erff(tt * 0.70710678118654752f));
            ((__hip_bfloat16*)Out)[oi] = __float2bfloat16(g);
          }
        }
      }
}

// ---------------------------------------------------------------------------
// Pair-balanced MFMA flash attention with XOR-swizzled LDS + reg prefetch.
// ---------------------------------------------------------------------------
__global__ __launch_bounds__(256, 2)
void attn_pair(const __hip_bfloat16* __restrict__ qkv, __hip_bfloat16* __restrict__ o)
{
  const int p = blockIdx.x;            // 0..3
  const int h = blockIdx.y, b = blockIdx.z;
  const int t0 = p, t1 = 7 - p;

  __shared__ __align__(16) __hip_bfloat16 Qs[2][64 * 64];
  __shared__ __align__(16) __hip_bfloat16 Ks[64 * 64];
  __shared__ __align__(16) __hip_bfloat16 Vt[64 * 64];   // (dh, key), swizzled
  __shared__ __align__(16) __hip_bfloat16 Ps[4][16 * 64];

  const int tid = threadIdx.x, lane = tid & 63, wave = tid >> 6;
  const int quad = lane >> 4, col = lane & 15;
  const size_t base = ((size_t)b * Ss) * 1536 + (size_t)h * 64;

  // stage Q for both tiles (swizzled)
  #pragma unroll
  for (int t = 0; t < 2; ++t) {
    const int tq = t ? t1 : t0;
    #pragma unroll
    for (int it = 0; it < 2; ++it) {
      int c = it * 256 + tid;
      int row = c >> 3, seg = c & 7;
      bf16x8 q8 = *reinterpret_cast<const bf16x8*>(
          qkv + base + (size_t)(tq * 64 + row) * 1536 + seg * 8);
      *reinterpret_cast<bf16x8*>(&Qs[t][swz(row, seg)]) = q8;
    }
  }

  bf16x8 kreg[2], vreg[2];
  auto load_kv = [&](int c0) {
    #pragma unroll
    for (int it = 0; it < 2; ++it) {
      int c = it * 256 + tid;
      kreg[it] = *reinterpret_cast<const bf16x8*>(
          qkv + base + 512 + (size_t)(c0 * 64 + (c >> 3)) * 1536 + (c & 7) * 8);
    }
    #pragma unroll
    for (int it = 0; it < 2; ++it) {
      int row = tid & 63, seg = it * 4 + wave;
      vreg[it] = *reinterpret_cast<const bf16x8*>(
          qkv + base + 1024 + (size_t)(c0 * 64 + row) * 1536 + seg * 8);
    }
  };
  auto store_kv = [&]() {
    #pragma unroll
    for (int it = 0; it < 2; ++it) {
      int c = it * 256 + tid;
      *reinterpret_cast<bf16x8*>(&Ks[swz(c >> 3, c & 7)]) = kreg[it];
    }
    #pragma unroll
    for (int it = 0; it < 2; ++it) {
      int row = tid & 63, seg = it * 4 + wave;
      union { bf16x8 v; __hip_bfloat16 e[8]; } u; u.v = vreg[it];
      #pragma unroll
      for (int j = 0; j < 8; ++j) {
        int d = seg * 8 + j;
        Vt[d * 64 + ((((row >> 3)) ^ (d & 7)) << 3) + (row & 7)] = u.e[j];
      }
    }
  };

  float  mrow[2][4], lsum[2][4];
  floatx4 accO[2][4];
  #pragma unroll
  for (int t = 0; t < 2; ++t)
    #pragma unroll
    for (int r = 0; r < 4; ++r) {
      mrow[t][r] = -1e30f; lsum[t][r] = 0.f;
      floatx4 z4 = {0.f, 0.f, 0.f, 0.f};
      accO[t][r] = z4;
    }

  auto compute_tile = [&](const __hip_bfloat16* Qt, int tq, int c,
                          float* mr, float* ls, floatx4* aO) {
    floatx4 accS[4];
    #pragma unroll
    for (int i = 0; i < 4; ++i) { floatx4 z4 = {0.f,0.f,0.f,0.f}; accS[i] = z4; }
    const int m = wave * 16 + col;
    #pragma unroll
    for (int kc = 0; kc < 2; ++kc) {
      bf16x8 aq = *reinterpret_cast<const bf16x8*>(&Qt[swz(m, kc * 4 + quad)]);
      #pragma unroll
      for (int ni = 0; ni < 4; ++ni) {
        bf16x8 bk = *reinterpret_cast<const bf16x8*>(&Ks[swz(ni * 16 + col, kc * 4 + quad)]);
        accS[ni] = __builtin_amdgcn_mfma_f32_16x16x32_bf16(aq, bk, accS[ni], 0, 0, 0);
      }
    }

    const bool diag = (c == tq);
    float sc[4][4];
    #pragma unroll
    for (int ni = 0; ni < 4; ++ni)
      #pragma unroll
      for (int r = 0; r < 4; ++r) {
        float s = accS[ni][r] * 0.125f;
        if (diag && (ni * 16 + col) > (wave * 16 + quad * 4 + r)) s = -1e30f;
        sc[ni][r] = s;
      }

    #pragma unroll
    for (int r = 0; r < 4; ++r) {
      float cm = fmaxf(fmaxf(sc[0][r], sc[1][r]), fmaxf(sc[2][r], sc[3][r]));
      #pragma unroll
      for (int off = 1; off < 16; off <<= 1) cm = fmaxf(cm, __shfl_xor(cm, off));
      float mnew = fmaxf(mr[r], cm);
      float alpha = __expf(mr[r] - mnew);
      mr[r] = mnew;
      float ps = 0.f;
      #pragma unroll
      for (int ni = 0; ni < 4; ++ni) {
        float pv = __expf(sc[ni][r] - mnew);
        sc[ni][r] = pv;
        ps += pv;
      }
      #pragma unroll
      for (int off = 1; off < 16; off <<= 1) ps += __shfl_xor(ps, off);
      ls[r] = ls[r] * alpha + ps;
      #pragma unroll
      for (int ni = 0; ni < 4; ++ni) aO[ni][r] *= alpha;
    }

    #pragma unroll
    for (int ni = 0; ni < 4; ++ni)
      #pragma unroll
      for (int r = 0; r < 4; ++r) {
        int prow = quad * 4 + r;
        int pseg = ni * 2 + (col >> 3);
        Ps[wave][prow * 64 + ((pseg ^ (prow & 7)) << 3) + (col & 7)] =
            __float2bfloat16(sc[ni][r]);
      }

    #pragma unroll
    for (int kc = 0; kc < 2; ++kc) {
      bf16x8 ap = *reinterpret_cast<const bf16x8*>(&Ps[wave][swz(col, kc * 4 + quad)]);
      #pragma unroll
      for (int ni = 0; ni < 4; ++ni) {
        bf16x8 bv = *reinterpret_cast<const bf16x8*>(&Vt[swz(ni * 16 + col, kc * 4 + quad)]);
        aO[ni] = __builtin_amdgcn_mfma_f32_16x16x32_bf16(ap, bv, aO[ni], 0, 0, 0);
      }
    }
  };

  load_kv(0);
  for (int c = 0; c <= t1; ++c) {
    __syncthreads();
    store_kv();
    __syncthreads();
    if (c < t1) load_kv(c + 1);
    compute_tile(Qs[1], t1, c, mrow[1], lsum[1], accO[1]);
    if (c <= t0) compute_tile(Qs[0], t0, c, mrow[0], lsum[0], accO[0]);
  }

  #pragma unroll
  for (int t = 0; t < 2; ++t) {
    const int tq = t ? t1 : t0;
    float inv[4];
    #pragma unroll
    for (int r = 0; r < 4; ++r) inv[r] = 1.f / lsum[t][r];
    #pragma unroll
    for (int ni = 0; ni < 4; ++ni)
      #pragma unroll
      for (int r = 0; r < 4; ++r) {
        int qg = tq * 64 + wave * 16 + quad * 4 + r;
        o[((size_t)b * Ss + qg) * INNERi + h * 64 + ni * 16 + col] =
            __float2bfloat16(accO[t][ni][r] * inv[r]);
      }
  }
}

// ---------------------------------------------------------------------------
// Epilogue gather: out[b,d,sp] = x[b, 255+sp, d]
// ---------------------------------------------------------------------------
__global__ void epilogue_kernel(const float* __restrict__ x, float* __restrict__ out)
{
  int idx = blockIdx.x * 256 + threadIdx.x;    // over B*D*256
  int sp = idx & 255;
  int bd = idx >> 8;
  int b = bd >> 9, d = bd & 511;
  out[idx] = x[((size_t)b * Ss + (NCc - 1) + sp) * Dd + d];
}

// ---------------------------------------------------------------------------
extern "C" void kernel_launch(void* const* d_in, const int* in_sizes, int n_in,
                              void* d_out, int out_size, void* d_ws, size_t ws_size,
                              hipStream_t stream)
{
  const float* z       = (const float*)d_in[0];
  const float* slots   = (const float*)d_in[1];
  const float* pos_emb = (const float*)d_in[2];
  const float* spos    = (const float*)d_in[3];
  const float* norm_w  = (const float*)d_in[4];
  const float* norm_b  = (const float*)d_in[5];
  const float* ln1_w   = (const float*)d_in[6];
  const float* ln1_b   = (const float*)d_in[7];
  const float* qkv_w   = (const float*)d_in[8];
  const float* out_w   = (const float*)d_in[9];
  const float* out_b   = (const float*)d_in[10];
  const float* ln2_w   = (const float*)d_in[11];
  const float* ln2_b   = (const float*)d_in[12];
  const float* mlp_w1  = (const float*)d_in[13];
  const float* mlp_b1  = (const float*)d_in[14];
  const float* mlp_w2  = (const float*)d_in[15];
  const float* mlp_b2  = (const float*)d_in[16];

  char* ws = (char*)d_ws;
  float*          xbuf = (float*)ws;
  __hip_bfloat16* ybuf = (__hip_bfloat16*)(ws + 33554432);
  __hip_bfloat16* qkvb = (__hip_bfloat16*)(ws + 50331648);
  __hip_bfloat16* obuf = (__hip_bfloat16*)(ws + 100663296);
  __hip_bfloat16* hbuf = (__hip_bfloat16*)(ws + 50331648);
  __hip_bfloat16* wT   = (__hip_bfloat16*)(ws + 117440512);

  const size_t WL = 3145728;

  // allow 128 KiB dynamic LDS for the 256^2 8-phase GEMMs
  hipFuncSetAttribute(reinterpret_cast<const void*>(&gemm256<0>),
                      hipFuncAttributeMaxDynamicSharedMemorySize, 131072);
  hipFuncSetAttribute(reinterpret_cast<const void*>(&gemm256<2>),
                      hipFuncAttributeMaxDynamicSharedMemorySize, 131072);

  dim3 tb(32, 8);
  transpose_w<<<dim3(1536 / 32, 512 / 32, 8), tb, 0, stream>>>(qkv_w,  wT + 0,       512, 1536, (size_t)512 * 1536, WL);
  transpose_w<<<dim3(512 / 32,  512 / 32, 8), tb, 0, stream>>>(out_w,  wT + 786432,  512, 512,  (size_t)512 * 512,  WL);
  transpose_w<<<dim3(2048 / 32, 512 / 32, 8), tb, 0, stream>>>(mlp_w1, wT + 1048576, 512, 2048, (size_t)512 * 2048, WL);
  transpose_w<<<dim3(512 / 32, 2048 / 32, 8), tb, 0, stream>>>(mlp_w2, wT + 2097152, 2048, 512, (size_t)2048 * 512, WL);

  prologue_kernel<<<Mrows, 64, 0, stream>>>(z, slots, pos_emb, spos, norm_w, norm_b, xbuf);

  for (int i = 0; i < 8; ++i) {
    const __hip_bfloat16* qkvT = wT + (size_t)i * WL;
    const __hip_bfloat16* outT = wT + (size_t)i * WL + 786432;
    const __hip_bfloat16* w1T  = wT + (size_t)i * WL + 1048576;
    const __hip_bfloat16* w2T  = wT + (size_t)i * WL + 2097152;

    ln_kernel<<<Mrows / 4, 256, 0, stream>>>(xbuf, ln1_w + i * Dd, ln1_b + i * Dd, ybuf);
    gemm256<0><<<dim3((1536 / 256) * (Mrows / 256)), 512, 131072, stream>>>(
        ybuf, qkvT, nullptr, qkvb, Mrows, 1536, 512);
    attn_pair<<<dim3(4, NHh, Bb), 256, 0, stream>>>(qkvb, obuf);
    gemm_bt<1><<<dim3((512 / 128) * (Mrows / 128)), 256, 0, stream>>>(
        obuf, outT, out_b + i * Dd, xbuf, xbuf, Mrows, 512, 512);
    ln_kernel<<<Mrows / 4, 256, 0, stream>>>(xbuf, ln2_w + i * Dd, ln2_b + i * Dd, ybuf);
    gemm256<2><<<dim3((2048 / 256) * (Mrows / 256)), 512, 131072, stream>>>(
        ybuf, w1T, mlp_b1 + i * MLPm, hbuf, Mrows, 2048, 512);
    gemm_bt<1><<<dim3((512 / 128) * (Mrows / 128)), 256, 0, stream>>>(
        hbuf, w2T, mlp_b2 + i * Dd, xbuf, xbuf, Mrows, 512, 2048);
  }

  epilogue_kernel<<<(Bb * Dd * 256) / 256, 256, 0, stream>>>(xbuf, (float*)d_out);
}